// Round 7
// baseline (155.078 us; speedup 1.0000x reference)
//
#include <hip/hip_runtime.h>

#define EPS 1e-12f

// MovingAvgNormNonBias: x [B=32, T=3000, D=512] fp32, kernel_size k (=100).
// Single-kernel: one block per (b, SEG=75-row chunk). Block computes its own
// init window sums (<=k rows, L2/L3-hot halo), then a 2x-unrolled software-
// pipelined streaming loop. Interior chunks: unmasked, denom==k,
// var = s2 - s1^2/k, rsqrt normalize. Edge chunks: masked general path.
// XCD swizzle keeps adjacent chunks of one batch on one XCD for halo reuse.

typedef float f4 __attribute__((ext_vector_type(4)));

constexpr int Bq = 32, Tq = 3000, Dq = 512;
constexpr int SEG = 75;
constexpr int NCHUNK = Tq / SEG;      // 40
constexpr int NB = Bq * NCHUNK;       // 1280 blocks
constexpr int NXCD = 8;

__global__ __launch_bounds__(128) void mavn_kernel(
    const float* __restrict__ x, const int* __restrict__ kptr,
    float* __restrict__ out)
{
    // XCD-swizzled decode of (b, chunk): adjacent chunks -> same XCD
    const int g = blockIdx.x;                  // 0..NB-1
    const int xcd = g & (NXCD - 1);
    const int slot = g >> 3;
    const int pair = xcd * (NB / NXCD) + slot;
    const int b = pair / NCHUNK;
    const int c = pair % NCHUNK;
    const int t0 = c * SEG;
    const int t1 = t0 + SEG;

    const int k = kptr[0];
    const int half = k >> 1;
    const int d4 = threadIdx.x;
    const size_t base = ((size_t)b * Tq) * (size_t)Dq + (size_t)d4 * 4;
    const float* xp = x + base;
    float* op = out + base;

    // ---- init window sums for t = t0: rows [t0-half, t0+k-half-1] clipped ----
    f4 s1 = {0.f, 0.f, 0.f, 0.f};
    f4 s2 = s1;
    {
        f4 a1 = s1, a2 = s1;           // second accumulator pair for ILP
        const int wlo = (t0 - half > 0) ? t0 - half : 0;
        const int whi = (t0 + (k - half) < Tq) ? t0 + (k - half) : Tq;
        int j = wlo;
        for (; j + 1 < whi; j += 2) {
            const f4 v = *(const f4*)(xp + (size_t)j * Dq);
            const f4 w = *(const f4*)(xp + (size_t)(j + 1) * Dq);
            s1 += v; s2 += v * v;
            a1 += w; a2 += w * w;
        }
        if (j < whi) {
            const f4 v = *(const f4*)(xp + (size_t)j * Dq);
            s1 += v; s2 += v * v;
        }
        s1 += a1; s2 += a2;
    }

    const float kf = (float)k;
    const float inv_km1 = 1.0f / (float)(k - 1);
    const int tail_start = Tq - (k - half);

    // interior: full window in-bounds and denom == k for every t in chunk
    const bool interior =
        (t0 >= half) && (t0 >= k - half) &&
        (t1 - 1 + (k - half) - 1 <= Tq - 1) &&
        (t1 - 1 < tail_start);

    if (interior) {
        const float inv_k = 1.0f / kf;
        // ---- peel j = 0 ----
        {
            const f4 xc = *(const f4*)(xp + (size_t)t0 * Dq);
            f4 o;
#pragma unroll
            for (int cc = 0; cc < 4; ++cc) {
                const float m = s1[cc] * inv_k;
                float var_sum = s2[cc] - m * s1[cc];
                var_sum = fmaxf(var_sum, 1e-12f);
                const float r = __builtin_amdgcn_rsqf(var_sum * inv_km1);
                o[cc] = (xc[cc] - m) * r;
            }
            __builtin_nontemporal_store(o, (f4*)(op + (size_t)t0 * Dq));
        }
        // ---- 2x-unrolled pipelined j = 1..SEG-1 (SEG-1 even: 37 pairs) ----
        // rows for step j: num = t0+j, in = t0+j+(k-half)-1, out = t0+j-half-1
        const int inoff = (k - half) - 1;      // +49
        const int oboff = -(half + 1);         // -51
        f4 n0 = *(const f4*)(xp + (size_t)(t0 + 1) * Dq);
        f4 n1 = *(const f4*)(xp + (size_t)(t0 + 2) * Dq);
        f4 i0 = *(const f4*)(xp + (size_t)(t0 + 1 + inoff) * Dq);
        f4 i1 = *(const f4*)(xp + (size_t)(t0 + 2 + inoff) * Dq);
        f4 o0 = *(const f4*)(xp + (size_t)(t0 + 1 + oboff) * Dq);
        f4 o1 = *(const f4*)(xp + (size_t)(t0 + 2 + oboff) * Dq);
        for (int j = 1; j < SEG; j += 2) {
            const f4 cn0 = n0, cn1 = n1, ci0 = i0, ci1 = i1, co0 = o0, co1 = o1;
            // prefetch next pair (clamped at the tail: reload current, L1-hot)
            {
                const int jn = (j + 2 <= SEG - 2) ? j + 2 : j;
                n0 = *(const f4*)(xp + (size_t)(t0 + jn) * Dq);
                n1 = *(const f4*)(xp + (size_t)(t0 + jn + 1) * Dq);
                i0 = *(const f4*)(xp + (size_t)(t0 + jn + inoff) * Dq);
                i1 = *(const f4*)(xp + (size_t)(t0 + jn + 1 + inoff) * Dq);
                o0 = *(const f4*)(xp + (size_t)(t0 + jn + oboff) * Dq);
                o1 = *(const f4*)(xp + (size_t)(t0 + jn + 1 + oboff) * Dq);
            }
            // step j
            s1 += ci0 - co0;
            s2 += ci0 * ci0 - co0 * co0;
            f4 oa;
#pragma unroll
            for (int cc = 0; cc < 4; ++cc) {
                const float m = s1[cc] * inv_k;
                float var_sum = s2[cc] - m * s1[cc];
                var_sum = fmaxf(var_sum, 1e-12f);
                const float r = __builtin_amdgcn_rsqf(var_sum * inv_km1);
                oa[cc] = (cn0[cc] - m) * r;
            }
            __builtin_nontemporal_store(oa, (f4*)(op + (size_t)(t0 + j) * Dq));
            // step j+1
            s1 += ci1 - co1;
            s2 += ci1 * ci1 - co1 * co1;
            f4 ob2;
#pragma unroll
            for (int cc = 0; cc < 4; ++cc) {
                const float m = s1[cc] * inv_k;
                float var_sum = s2[cc] - m * s1[cc];
                var_sum = fmaxf(var_sum, 1e-12f);
                const float r = __builtin_amdgcn_rsqf(var_sum * inv_km1);
                ob2[cc] = (cn1[cc] - m) * r;
            }
            __builtin_nontemporal_store(ob2, (f4*)(op + (size_t)(t0 + j + 1) * Dq));
        }
        return;
    }

    // ---- general (edge) path: masked pipelined loop ----
    f4 nx = *(const f4*)(xp + (size_t)t0 * Dq);
    f4 ia = {0.f, 0.f, 0.f, 0.f};
    f4 ob = ia;
    float wa = 0.f, wb = 0.f;

    for (int t = t0; t < t1; ++t) {
        const f4 cnum = nx;
        const f4 cin = ia;
        const f4 cout = ob;
        const float cwa = wa, cwb = wb;

        {
            const int tn = (t + 1 < t1) ? t + 1 : t;
            nx = *(const f4*)(xp + (size_t)tn * Dq);
            int ja = tn + (k - half) - 1;
            int jr = tn - half - 1;
            wa = (ja < Tq && tn > t0) ? 1.f : 0.f;
            wb = (jr >= 0 && tn > t0) ? 1.f : 0.f;
            ja = ja < Tq - 1 ? ja : Tq - 1; ja = ja > 0 ? ja : 0;
            jr = jr > 0 ? jr : 0;
            ia = *(const f4*)(xp + (size_t)ja * Dq);
            ob = *(const f4*)(xp + (size_t)jr * Dq);
        }

        s1 += cwa * cin - cwb * cout;
        s2 += cwa * cin * cin - cwb * cout * cout;

        // branchless denom: ramp half..k-1, flat k, ramp k-1..half
        int idn = half + t;
        idn = idn < k ? idn : k;
        const int tail = (k - 1) - (t - tail_start);
        idn = idn < tail ? idn : tail;
        const float inv_denom = __builtin_amdgcn_rcpf((float)idn);

        f4 o;
#pragma unroll
        for (int cc = 0; cc < 4; ++cc) {
            const float m = s1[cc] * inv_denom;
            float var_sum = s2[cc] - 2.0f * m * s1[cc] + kf * m * m;
            var_sum = fmaxf(var_sum, 0.0f);
            const float sd = __builtin_amdgcn_sqrtf(var_sum * inv_km1);
            o[cc] = (cnum[cc] - m) * __builtin_amdgcn_rcpf(sd + EPS);
        }
        __builtin_nontemporal_store(o, (f4*)(op + (size_t)t * Dq));
    }
}

extern "C" void kernel_launch(void* const* d_in, const int* in_sizes, int n_in,
                              void* d_out, int out_size, void* d_ws, size_t ws_size,
                              hipStream_t stream) {
    const float* x = (const float*)d_in[0];
    const int* kptr = (const int*)d_in[1];
    float* out = (float*)d_out;
    (void)in_sizes; (void)n_in; (void)out_size; (void)d_ws; (void)ws_size;

    mavn_kernel<<<NB, 128, 0, stream>>>(x, kptr, out);
}

// Round 8
// 113.163 us; speedup vs baseline: 1.3704x; 1.3704x over previous
//
#include <hip/hip_runtime.h>

#define EPS 1e-12f

// MovingAvgNormNonBias: x [B=32, T=3000, D=512] fp32, k=100.
// Fused single kernel. Block = 512 threads = 8 waves = 4 T-chunks x 2 D-halves,
// covering 100 rows. Phase 1: waves cooperatively compute 7 segment sums
// (4 own + 3 halo, 25 rows each, per D-half) into LDS -- 7680 waves total so
// the cold HBM read streams at full BW (R7 lesson: wave count is the binding
// resource for the cold phase). Phase 2: each wave inits its window from 4 LDS
// segment sums (k==100 -> exactly 4 segs) and runs the software-pipelined
// streaming loop on its 25 rows x 256 cols. Interior: unmasked, denom==k,
// var = s2 - s1^2/k, rsqrt. Edges / k!=100: masked general path, inline init.
// XCD swizzle: adjacent row-groups of one batch on one XCD for halo L2 reuse.

typedef float f4 __attribute__((ext_vector_type(4)));

constexpr int Bq = 32, Tq = 3000, Dq = 512;
constexpr int SEGR = 25;             // rows per chunk (one wave's T-span)
constexpr int WT = 4;                // T-chunks per block
constexpr int TB = SEGR * WT;        // 100 rows per block
constexpr int NCHUNK = Tq / SEGR;    // 120
constexpr int NGRP = Tq / TB;        // 30 row-groups per batch
constexpr int NB = Bq * NGRP;        // 960 blocks
constexpr int NXCD = 8;
constexpr int NSEGL = WT + 3;        // 7 LDS segments: block-relative -2..+4

__global__ __launch_bounds__(512, 4) void mavn_kernel(
    const float* __restrict__ x, const int* __restrict__ kptr,
    float* __restrict__ out)
{
    __shared__ float lds1[NSEGL][Dq];   // 14 KB
    __shared__ float lds2[NSEGL][Dq];   // 14 KB

    // XCD-swizzled decode: adjacent slots -> adjacent row-groups, same batch
    const int g = blockIdx.x;
    const int xcd = g & (NXCD - 1);
    const int slot = g >> 3;
    const int pair = xcd * (NB / NXCD) + slot;
    const int b = pair / NGRP;
    const int grp = pair % NGRP;
    const int c0 = grp * WT;            // first chunk index of this block

    const int tid = threadIdx.x;
    const int w = tid >> 6;             // wave 0..7
    const int l = tid & 63;
    const int tw = w >> 1;              // 0..3: T-chunk within block
    const int dh = w & 1;               // 0..1: D-half

    const int k = kptr[0];
    const int half = k >> 1;

    const size_t bbase = (size_t)b * Tq * Dq;
    const int doff = dh * (Dq / 2) + l * 4;      // float offset of this lane's f4

    // ---- phase 1: cooperative segment sums into LDS (k==100 only) ----
    if (k == 4 * SEGR) {
        for (int tk = w; tk < 2 * NSEGL; tk += 8) {
            const int si = tk % NSEGL;           // LDS row 0..6
            const int sdh = tk / NSEGL;          // D-half of this task
            const int cs = c0 + si - 2;          // global chunk index
            if (cs >= 0 && cs < NCHUNK) {
                const float* sp = x + bbase + (size_t)(cs * SEGR) * Dq
                                  + sdh * (Dq / 2) + l * 4;
                f4 a1 = {0.f, 0.f, 0.f, 0.f};
                f4 a2 = a1, c1 = a1, c2 = a1;
#pragma unroll 5
                for (int j = 0; j < SEGR; j += 2) {
                    const f4 v = *(const f4*)(sp + (size_t)j * Dq);
                    a1 += v; a2 += v * v;
                    if (j + 1 < SEGR) {
                        const f4 u = *(const f4*)(sp + (size_t)(j + 1) * Dq);
                        c1 += u; c2 += u * u;
                    }
                }
                ((f4*)&lds1[si][sdh * (Dq / 2)])[l] = a1 + c1;
                ((f4*)&lds2[si][sdh * (Dq / 2)])[l] = a2 + c2;
            }
        }
    }
    __syncthreads();

    // ---- phase 2: per-wave streaming normalize of its 25 rows ----
    const int c = c0 + tw;
    const int t0 = c * SEGR;
    const int t1 = t0 + SEGR;
    const float kf = (float)k;
    const float inv_km1 = 1.0f / (float)(k - 1);
    const int tail_start = Tq - (k - half);
    const float* xp = x + bbase + doff;
    float* op = out + bbase + doff;

    // interior: full window in-bounds AND denom == k for every t in chunk
    const bool interior = (k == 4 * SEGR) && (t0 >= half) &&
                          (t0 + SEGR - 1 + (k - half) - 1 <= Tq - 1) &&
                          (t0 + SEGR - 1 < tail_start);

    if (interior) {
        // init from LDS segment sums: window [t0-50, t0+49] = LDS rows tw..tw+3
        f4 s1 = {0.f, 0.f, 0.f, 0.f};
        f4 s2 = s1;
#pragma unroll
        for (int i = 0; i < 4; ++i) {
            s1 += ((const f4*)&lds1[tw + i][dh * (Dq / 2)])[l];
            s2 += ((const f4*)&lds2[tw + i][dh * (Dq / 2)])[l];
        }
        const float inv_k = 1.0f / kf;
        // peel j = 0
        {
            const f4 xc = *(const f4*)(xp + (size_t)t0 * Dq);
            f4 o;
#pragma unroll
            for (int cc = 0; cc < 4; ++cc) {
                const float m = s1[cc] * inv_k;
                float var_sum = s2[cc] - m * s1[cc];
                var_sum = fmaxf(var_sum, 1e-12f);
                const float r = __builtin_amdgcn_rsqf(var_sum * inv_km1);
                o[cc] = (xc[cc] - m) * r;
            }
            __builtin_nontemporal_store(o, (f4*)(op + (size_t)t0 * Dq));
        }
        // 2x-unrolled pipelined j = 1..24 (12 exact pairs)
        const int inoff = (k - half) - 1;      // +49
        const int oboff = -(half + 1);         // -51
        f4 n0 = *(const f4*)(xp + (size_t)(t0 + 1) * Dq);
        f4 n1 = *(const f4*)(xp + (size_t)(t0 + 2) * Dq);
        f4 i0 = *(const f4*)(xp + (size_t)(t0 + 1 + inoff) * Dq);
        f4 i1 = *(const f4*)(xp + (size_t)(t0 + 2 + inoff) * Dq);
        f4 o0 = *(const f4*)(xp + (size_t)(t0 + 1 + oboff) * Dq);
        f4 o1 = *(const f4*)(xp + (size_t)(t0 + 2 + oboff) * Dq);
        for (int j = 1; j < SEGR; j += 2) {
            const f4 cn0 = n0, cn1 = n1, ci0 = i0, ci1 = i1, co0 = o0, co1 = o1;
            {
                const int jn = (j + 2 <= SEGR - 2) ? j + 2 : j;  // tail: reload (L1-hot)
                n0 = *(const f4*)(xp + (size_t)(t0 + jn) * Dq);
                n1 = *(const f4*)(xp + (size_t)(t0 + jn + 1) * Dq);
                i0 = *(const f4*)(xp + (size_t)(t0 + jn + inoff) * Dq);
                i1 = *(const f4*)(xp + (size_t)(t0 + jn + 1 + inoff) * Dq);
                o0 = *(const f4*)(xp + (size_t)(t0 + jn + oboff) * Dq);
                o1 = *(const f4*)(xp + (size_t)(t0 + jn + 1 + oboff) * Dq);
            }
            // step j
            s1 += ci0 - co0;
            s2 += ci0 * ci0 - co0 * co0;
            f4 oa;
#pragma unroll
            for (int cc = 0; cc < 4; ++cc) {
                const float m = s1[cc] * inv_k;
                float var_sum = s2[cc] - m * s1[cc];
                var_sum = fmaxf(var_sum, 1e-12f);
                const float r = __builtin_amdgcn_rsqf(var_sum * inv_km1);
                oa[cc] = (cn0[cc] - m) * r;
            }
            __builtin_nontemporal_store(oa, (f4*)(op + (size_t)(t0 + j) * Dq));
            // step j+1
            s1 += ci1 - co1;
            s2 += ci1 * ci1 - co1 * co1;
            f4 ob;
#pragma unroll
            for (int cc = 0; cc < 4; ++cc) {
                const float m = s1[cc] * inv_k;
                float var_sum = s2[cc] - m * s1[cc];
                var_sum = fmaxf(var_sum, 1e-12f);
                const float r = __builtin_amdgcn_rsqf(var_sum * inv_km1);
                ob[cc] = (cn1[cc] - m) * r;
            }
            __builtin_nontemporal_store(ob, (f4*)(op + (size_t)(t0 + j + 1) * Dq));
        }
        return;
    }

    // ---- general (edge / k!=100) path: inline init + masked pipelined loop ----
    f4 s1 = {0.f, 0.f, 0.f, 0.f};
    f4 s2 = s1;
    {
        const int wlo = (t0 - half > 0) ? t0 - half : 0;
        const int whi = (t0 + (k - half) < Tq) ? t0 + (k - half) : Tq;
        f4 a1 = s1, a2 = s1;
        int j = wlo;
        for (; j + 1 < whi; j += 2) {
            const f4 v = *(const f4*)(xp + (size_t)j * Dq);
            const f4 u = *(const f4*)(xp + (size_t)(j + 1) * Dq);
            s1 += v; s2 += v * v;
            a1 += u; a2 += u * u;
        }
        if (j < whi) {
            const f4 v = *(const f4*)(xp + (size_t)j * Dq);
            s1 += v; s2 += v * v;
        }
        s1 += a1; s2 += a2;
    }

    f4 nx = *(const f4*)(xp + (size_t)t0 * Dq);
    f4 ia = {0.f, 0.f, 0.f, 0.f};
    f4 ob = ia;
    float wa = 0.f, wb = 0.f;

    for (int t = t0; t < t1; ++t) {
        const f4 cnum = nx;
        const f4 cin = ia;
        const f4 cout = ob;
        const float cwa = wa, cwb = wb;

        {
            const int tn = (t + 1 < t1) ? t + 1 : t;
            nx = *(const f4*)(xp + (size_t)tn * Dq);
            int ja = tn + (k - half) - 1;
            int jr = tn - half - 1;
            wa = (ja < Tq && tn > t0) ? 1.f : 0.f;
            wb = (jr >= 0 && tn > t0) ? 1.f : 0.f;
            ja = ja < Tq - 1 ? ja : Tq - 1; ja = ja > 0 ? ja : 0;
            jr = jr > 0 ? jr : 0;
            ia = *(const f4*)(xp + (size_t)ja * Dq);
            ob = *(const f4*)(xp + (size_t)jr * Dq);
        }

        s1 += cwa * cin - cwb * cout;
        s2 += cwa * cin * cin - cwb * cout * cout;

        // branchless denom: ramp half..k-1, flat k, ramp k-1..half
        int idn = half + t;
        idn = idn < k ? idn : k;
        const int tail = (k - 1) - (t - tail_start);
        idn = idn < tail ? idn : tail;
        const float inv_denom = __builtin_amdgcn_rcpf((float)idn);

        f4 o;
#pragma unroll
        for (int cc = 0; cc < 4; ++cc) {
            const float m = s1[cc] * inv_denom;
            float var_sum = s2[cc] - 2.0f * m * s1[cc] + kf * m * m;
            var_sum = fmaxf(var_sum, 0.0f);
            const float sd = __builtin_amdgcn_sqrtf(var_sum * inv_km1);
            o[cc] = (cnum[cc] - m) * __builtin_amdgcn_rcpf(sd + EPS);
        }
        __builtin_nontemporal_store(o, (f4*)(op + (size_t)t * Dq));
    }
}

extern "C" void kernel_launch(void* const* d_in, const int* in_sizes, int n_in,
                              void* d_out, int out_size, void* d_ws, size_t ws_size,
                              hipStream_t stream) {
    const float* x = (const float*)d_in[0];
    const int* kptr = (const int*)d_in[1];
    float* out = (float*)d_out;
    (void)in_sizes; (void)n_in; (void)out_size; (void)d_ws; (void)ws_size;

    mavn_kernel<<<NB, 512, 0, stream>>>(x, kptr, out);
}